// Round 3
// baseline (1728.710 us; speedup 1.0000x reference)
//
#include <hip/hip_runtime.h>
#include <stdint.h>

// ---------------------------------------------------------------------------
// Net_29137058136132: ImgEncoder (2048->512) + 6x Rs_GCN non-local blocks.
// B=256, N=100, C=512, DIMG=2048, L=6.
// ALL inputs and the output are fp32 (per reference). Internally: bf16 MFMA
// with fp32 accumulation. Weights pre-converted fp32->bf16 once per call;
// activations converted during LDS staging. Residual master x stays fp32 in
// d_out (final value of x IS the output).
// Workspace: wbf(14MB) + buf1(26.2MB) + buf2(26.2MB) + R(6.55MB) ~= 73MB.
// ---------------------------------------------------------------------------

typedef __bf16 bf16;
typedef float  f32x4  __attribute__((ext_vector_type(4)));
typedef bf16   bf16x4 __attribute__((ext_vector_type(4)));
typedef bf16   bf16x8 __attribute__((ext_vector_type(8)));

#define MTOT   25600   // 256*100 rows
#define CDIM   512
#define NTOK   100
#define RPAD   128     // padded K for R (cols 100..127 zeroed by memset)
#define BN_EPS 1e-5f

// ---------------- fp32 -> bf16 elementwise convert (n % 4 == 0) ------------
__global__ __launch_bounds__(256) void k_cvt(const float* __restrict__ s,
                                             bf16* __restrict__ d, int n)
{
    const int i = (blockIdx.x * 256 + threadIdx.x) * 4;
    if (i < n) {
        const f32x4 v = *(const f32x4*)(s + i);
        bf16x4 o;
#pragma unroll
        for (int e = 0; e < 4; ++e) o[e] = (bf16)v[e];
        *(bf16x4*)(d + i) = o;
    }
}

// ---------------------------------------------------------------------------
// 128x128-tile GEMM mainloop: C += A[m0:,:] * W[n0:,:]^T, BK=32, K%32==0.
// A: MxK row-major (fp32 if AF32 else bf16); W: 512xK row-major bf16.
// Block = 256 thr = 4 waves (2x2 of 64x64); wave does 4x4 16x16x32 MFMAs.
// ---------------------------------------------------------------------------
template<bool AF32>
__device__ __forceinline__ void gemm_tile(const void* __restrict__ A,
                                          const bf16* __restrict__ W,
                                          int K, int m0, int n0,
                                          bf16* As, bf16* Bs, f32x4 acc[4][4])
{
    const int tid  = threadIdx.x;
    const int lane = tid & 63, wave = tid >> 6;
    const int lrow = lane & 15, quad = lane >> 4;
    const int wm = (wave & 1) * 64, wn = (wave >> 1) * 64;

    for (int kt = 0; kt < K; kt += 32) {
        bf16x8 av[2], wv[2];
#pragma unroll
        for (int u = 0; u < 2; ++u) {
            const int s  = tid + u * 256;      // slot 0..511
            const int ar = s >> 2;             // tile row 0..127
            const int kp = (s & 3) * 8;        // k offset 0,8,16,24
            if (AF32) {
                const float* ap = (const float*)A + (size_t)(m0 + ar) * K + kt + kp;
                const f32x4 f0 = *(const f32x4*)ap;
                const f32x4 f1 = *(const f32x4*)(ap + 4);
#pragma unroll
                for (int e = 0; e < 4; ++e) {
                    av[u][e]     = (bf16)f0[e];
                    av[u][e + 4] = (bf16)f1[e];
                }
            } else {
                av[u] = *(const bf16x8*)((const bf16*)A + (size_t)(m0 + ar) * K + kt + kp);
            }
            wv[u] = *(const bf16x8*)(W + (size_t)(n0 + ar) * K + kt + kp);
        }
        __syncthreads();   // previous iteration's fragment reads complete
#pragma unroll
        for (int u = 0; u < 2; ++u) {
            const int s  = tid + u * 256;
            const int ar = s >> 2;
            const int kp = (s & 3) * 8;
            *(bf16x8*)(As + ar * 32 + kp) = av[u];
            *(bf16x8*)(Bs + ar * 32 + kp) = wv[u];
        }
        __syncthreads();
        bf16x8 af[4], bv[4];
#pragma unroll
        for (int i = 0; i < 4; ++i)
            af[i] = *(const bf16x8*)(As + (wm + i * 16 + lrow) * 32 + quad * 8);
#pragma unroll
        for (int j = 0; j < 4; ++j)
            bv[j] = *(const bf16x8*)(Bs + (wn + j * 16 + lrow) * 32 + quad * 8);
#pragma unroll
        for (int i = 0; i < 4; ++i)
#pragma unroll
            for (int j = 0; j < 4; ++j)
                acc[i][j] = __builtin_amdgcn_mfma_f32_16x16x32_bf16(
                    af[i], bv[j], acc[i][j], 0, 0, 0);
    }
}

// ---------------- Encoder: xf = img @ trans_w^T + b (fp32 A, fp32 out) -----
__global__ __launch_bounds__(256) void k_enc(const float* __restrict__ img,
                                             const bf16* __restrict__ Wt,
                                             const float* __restrict__ bias,
                                             float* __restrict__ xf)
{
    __shared__ __align__(16) bf16 As[128 * 32];
    __shared__ __align__(16) bf16 Bs[128 * 32];
    const int m0 = blockIdx.y * 128, n0 = blockIdx.x * 128;
    f32x4 acc[4][4] = {};
    gemm_tile<true>(img, Wt, 2048, m0, n0, As, Bs, acc);

    const int tid = threadIdx.x, wave = tid >> 6, lane = tid & 63;
    const int lrow = lane & 15, quad = lane >> 4;
    const int wm = (wave & 1) * 64, wn = (wave >> 1) * 64;
#pragma unroll
    for (int j = 0; j < 4; ++j) {
        const int col = n0 + wn + j * 16 + lrow;
        const float b = bias[col];
#pragma unroll
        for (int i = 0; i < 4; ++i) {
            const int row0 = m0 + wm + i * 16 + quad * 4;
#pragma unroll
            for (int r = 0; r < 4; ++r)
                xf[(size_t)(row0 + r) * CDIM + col] = acc[i][j][r] + b;
        }
    }
}

// ---------------- Projection(s): out = bf16(x @ W^T + b), x fp32 -----------
// grid.z in {1,2}: z==0 -> (W0,b0,o0), z==1 -> (W1,b1,o1).
__global__ __launch_bounds__(256) void k_proj2(const float* __restrict__ xf,
                                               const bf16* __restrict__ W0, const float* __restrict__ b0,
                                               bf16* __restrict__ o0,
                                               const bf16* __restrict__ W1, const float* __restrict__ b1,
                                               bf16* __restrict__ o1)
{
    __shared__ __align__(16) bf16 As[128 * 32];
    __shared__ __align__(16) bf16 Bs[128 * 32];
    const bf16*  W    = blockIdx.z ? W1 : W0;
    const float* bias = blockIdx.z ? b1 : b0;
    bf16*        out  = blockIdx.z ? o1 : o0;

    const int m0 = blockIdx.y * 128, n0 = blockIdx.x * 128;
    f32x4 acc[4][4] = {};
    gemm_tile<true>(xf, W, 512, m0, n0, As, Bs, acc);

    const int tid = threadIdx.x, wave = tid >> 6, lane = tid & 63;
    const int lrow = lane & 15, quad = lane >> 4;
    const int wm = (wave & 1) * 64, wn = (wave >> 1) * 64;
#pragma unroll
    for (int j = 0; j < 4; ++j) {
        const int col = n0 + wn + j * 16 + lrow;
        const float b = bias[col];
#pragma unroll
        for (int i = 0; i < 4; ++i) {
            const int row0 = m0 + wm + i * 16 + quad * 4;
#pragma unroll
            for (int r = 0; r < 4; ++r)
                out[(size_t)(row0 + r) * CDIM + col] = (bf16)(acc[i][j][r] + b);
        }
    }
}

// ---------------- W-proj + BN(eval) + residual (updates fp32 xf) -----------
__global__ __launch_bounds__(256) void k_wproj(const bf16* __restrict__ Y,
                                               const bf16* __restrict__ Wt,
                                               const float* __restrict__ bias,
                                               const float* __restrict__ bng, const float* __restrict__ bnb,
                                               const float* __restrict__ bnm, const float* __restrict__ bnv,
                                               float* __restrict__ xf)
{
    __shared__ __align__(16) bf16 As[128 * 32];
    __shared__ __align__(16) bf16 Bs[128 * 32];
    const int m0 = blockIdx.y * 128, n0 = blockIdx.x * 128;
    f32x4 acc[4][4] = {};
    gemm_tile<false>(Y, Wt, 512, m0, n0, As, Bs, acc);

    const int tid = threadIdx.x, wave = tid >> 6, lane = tid & 63;
    const int lrow = lane & 15, quad = lane >> 4;
    const int wm = (wave & 1) * 64, wn = (wave >> 1) * 64;
#pragma unroll
    for (int j = 0; j < 4; ++j) {
        const int col = n0 + wn + j * 16 + lrow;
        const float sc = bng[col] * rsqrtf(bnv[col] + BN_EPS);
        const float sh = (bias[col] - bnm[col]) * sc + bnb[col];
#pragma unroll
        for (int i = 0; i < 4; ++i) {
            const int row0 = m0 + wm + i * 16 + quad * 4;
#pragma unroll
            for (int r = 0; r < 4; ++r) {
                const size_t idx = (size_t)(row0 + r) * CDIM + col;
                xf[idx] += acc[i][j][r] * sc + sh;
            }
        }
    }
}

// ---------------- R = th @ ph^T / 100, per batch ---------------------------
__global__ __launch_bounds__(256) void k_R(const bf16* __restrict__ TH,
                                           const bf16* __restrict__ PH,
                                           bf16* __restrict__ R)
{
    const int b = blockIdx.x;
    const bf16* th = TH + (size_t)b * NTOK * CDIM;
    const bf16* ph = PH + (size_t)b * NTOK * CDIM;
    bf16* Rb = R + (size_t)b * NTOK * RPAD;
    const int tid = threadIdx.x, wave = tid >> 6, lane = tid & 63;
    const int lrow = lane & 15, quad = lane >> 4;

    f32x4 acc[2][7] = {};
    for (int kt = 0; kt < CDIM; kt += 32) {
        bf16x8 af[2], bv[7];
#pragma unroll
        for (int i = 0; i < 2; ++i) {
            int row = (wave * 2 + i) * 16 + lrow; if (row > 99) row = 99;
            af[i] = *(const bf16x8*)(th + (size_t)row * CDIM + kt + quad * 8);
        }
#pragma unroll
        for (int j = 0; j < 7; ++j) {
            int row = j * 16 + lrow; if (row > 99) row = 99;
            bv[j] = *(const bf16x8*)(ph + (size_t)row * CDIM + kt + quad * 8);
        }
#pragma unroll
        for (int i = 0; i < 2; ++i)
#pragma unroll
            for (int j = 0; j < 7; ++j)
                acc[i][j] = __builtin_amdgcn_mfma_f32_16x16x32_bf16(
                    af[i], bv[j], acc[i][j], 0, 0, 0);
    }
#pragma unroll
    for (int i = 0; i < 2; ++i) {
        const int row0 = (wave * 2 + i) * 16 + quad * 4;
#pragma unroll
        for (int j = 0; j < 7; ++j) {
            const int col = j * 16 + lrow;
#pragma unroll
            for (int r = 0; r < 4; ++r) {
                const int row = row0 + r;
                if (row < NTOK && col < NTOK)
                    Rb[row * RPAD + col] = (bf16)(acc[i][j][r] * 0.01f);
            }
        }
    }
}

// ---------------- y = R @ g, per batch -------------------------------------
__global__ __launch_bounds__(256) void k_y(const bf16* __restrict__ R,
                                           const bf16* __restrict__ G,
                                           bf16* __restrict__ Y)
{
    const int b = blockIdx.y, cc0 = blockIdx.x * 128;
    const bf16* Rb = R + (size_t)b * NTOK * RPAD;
    const bf16* Gb = G + (size_t)b * NTOK * CDIM;
    bf16* Yb = Y + (size_t)b * NTOK * CDIM;
    __shared__ __align__(16) bf16 Bt[128 * 40];   // [col][k], stride 40
    const int tid = threadIdx.x, wave = tid >> 6, lane = tid & 63;
    const int lrow = lane & 15, quad = lane >> 4;

    f32x4 acc[7][2] = {};
    for (int kt = 0; kt < RPAD; kt += 32) {
        __syncthreads();
#pragma unroll
        for (int i = 0; i < 2; ++i) {
            const int chunk = tid * 2 + i;       // 0..511
            const int kk = chunk >> 4;           // 0..31
            const int c8 = (chunk & 15) * 8;     // col base 0..120
            uint4 v; v.x = v.y = v.z = v.w = 0u;
            if (kt + kk < NTOK)
                v = *(const uint4*)(Gb + (size_t)(kt + kk) * CDIM + cc0 + c8);
            const bf16* pv = (const bf16*)&v;
#pragma unroll
            for (int e = 0; e < 8; ++e) Bt[(c8 + e) * 40 + kk] = pv[e];
        }
        __syncthreads();
        bf16x8 af[7], bv[2];
#pragma unroll
        for (int mt = 0; mt < 7; ++mt) {
            int row = mt * 16 + lrow; if (row > 99) row = 99;
            af[mt] = *(const bf16x8*)(Rb + (size_t)row * RPAD + kt + quad * 8);
        }
#pragma unroll
        for (int jj = 0; jj < 2; ++jj)
            bv[jj] = *(const bf16x8*)(Bt + ((wave * 2 + jj) * 16 + lrow) * 40 + quad * 8);
#pragma unroll
        for (int mt = 0; mt < 7; ++mt)
#pragma unroll
            for (int jj = 0; jj < 2; ++jj)
                acc[mt][jj] = __builtin_amdgcn_mfma_f32_16x16x32_bf16(
                    af[mt], bv[jj], acc[mt][jj], 0, 0, 0);
    }
#pragma unroll
    for (int mt = 0; mt < 7; ++mt) {
        const int row0 = mt * 16 + quad * 4;
#pragma unroll
        for (int jj = 0; jj < 2; ++jj) {
            const int col = cc0 + (wave * 2 + jj) * 16 + lrow;
#pragma unroll
            for (int r = 0; r < 4; ++r) {
                const int row = row0 + r;
                if (row < NTOK) Yb[(size_t)row * CDIM + col] = (bf16)acc[mt][jj][r];
            }
        }
    }
}

// ---------------------------------------------------------------------------
extern "C" void kernel_launch(void* const* d_in, const int* in_sizes, int n_in,
                              void* d_out, int out_size, void* d_ws, size_t ws_size,
                              hipStream_t stream)
{
    const float* img     = (const float*)d_in[0];
    const float* trans_w = (const float*)d_in[1];
    const float* trans_b = (const float*)d_in[2];
    const float* gw = (const float*)d_in[3],  *gb = (const float*)d_in[4];
    const float* tw = (const float*)d_in[5],  *tb = (const float*)d_in[6];
    const float* pw = (const float*)d_in[7],  *pb = (const float*)d_in[8];
    const float* ww = (const float*)d_in[9],  *wb = (const float*)d_in[10];
    const float* bng = (const float*)d_in[11], *bnb = (const float*)d_in[12];
    const float* bnm = (const float*)d_in[13], *bnv = (const float*)d_in[14];

    float* xf = (float*)d_out;                     // fp32 residual master == output

    // workspace: bf16 weights | buf1 | buf2 | R  ~= 73MB
    char* ws = (char*)d_ws;
    const size_t NW_T = (size_t)2048 * 512;        // trans_w elems
    const size_t NW_L = (size_t)6 * 512 * 512;     // per weight-tensor elems (all layers)
    bf16* twbf = (bf16*)ws;                        // 2 MB
    bf16* gwbf = twbf + NW_T;                      // 3 MB
    bf16* t2bf = gwbf + NW_L;
    bf16* pwbf = t2bf + NW_L;
    bf16* wwbf = pwbf + NW_L;
    bf16* buf1 = wwbf + NW_L;                      // 26.2 MB
    bf16* buf2 = buf1 + (size_t)MTOT * CDIM;       // 26.2 MB
    bf16* R    = buf2 + (size_t)MTOT * CDIM;       // 6.55 MB
    const size_t R_B = (size_t)256 * NTOK * RPAD * 2;

    hipMemsetAsync(R, 0, R_B, stream);             // zero K-pad cols of R

    const dim3 blk(256, 1, 1);
    k_cvt<<<dim3((int)(NW_T / 1024)), blk, 0, stream>>>(trans_w, twbf, (int)NW_T);
    k_cvt<<<dim3((int)(NW_L / 1024)), blk, 0, stream>>>(gw, gwbf, (int)NW_L);
    k_cvt<<<dim3((int)(NW_L / 1024)), blk, 0, stream>>>(tw, t2bf, (int)NW_L);
    k_cvt<<<dim3((int)(NW_L / 1024)), blk, 0, stream>>>(pw, pwbf, (int)NW_L);
    k_cvt<<<dim3((int)(NW_L / 1024)), blk, 0, stream>>>(ww, wwbf, (int)NW_L);

    k_enc<<<dim3(4, 200, 1), blk, 0, stream>>>(img, twbf, trans_b, xf);

    for (int l = 0; l < 6; ++l) {
        const size_t wo = (size_t)l * CDIM * CDIM, bo = (size_t)l * CDIM;
        // th -> buf1, ph -> buf2
        k_proj2<<<dim3(4, 200, 2), blk, 0, stream>>>(xf, t2bf + wo, tb + bo, buf1,
                                                     pwbf + wo, pb + bo, buf2);
        k_R<<<dim3(256, 1, 1), blk, 0, stream>>>(buf1, buf2, R);
        // g -> buf1 (th dead)
        k_proj2<<<dim3(4, 200, 1), blk, 0, stream>>>(xf, gwbf + wo, gb + bo, buf1,
                                                     gwbf + wo, gb + bo, buf1);
        // y -> buf2 (ph dead)
        k_y<<<dim3(4, 256, 1), blk, 0, stream>>>(R, buf1, buf2);
        k_wproj<<<dim3(4, 200, 1), blk, 0, stream>>>(buf2, wwbf + wo, wb + bo,
                                                     bng + bo, bnb + bo,
                                                     bnm + bo, bnv + bo, xf);
    }
}

// Round 4
// 1583.864 us; speedup vs baseline: 1.0915x; 1.0915x over previous
//
#include <hip/hip_runtime.h>
#include <stdint.h>

// ---------------------------------------------------------------------------
// Net_29137058136132: ImgEncoder (2048->512) + 6x Rs_GCN non-local blocks.
// B=256, N=100, C=512, DIMG=2048, L=6. fp32 in/out; bf16 MFMA, fp32 accum.
// Residual master x stays fp32 in d_out; bf16 shadow xb feeds projections.
// Staging via __builtin_amdgcn_global_load_lds width=16 (m97 structure).
// Workspace paths (runtime-selected on ws_size):
//   FULL >=205MB: weights|buf1|buf2|R|xb|imgb  (bf16 img for encoder)
//   MID  >=100MB: weights|buf1|buf2|R|xb       (fp32 img staging in encoder)
//   MIN  >= 73MB: weights|buf1|buf2|R          (round-3 fp32-A path, proven)
// ---------------------------------------------------------------------------

typedef __bf16 bf16;
typedef float  f32x4  __attribute__((ext_vector_type(4)));
typedef bf16   bf16x4 __attribute__((ext_vector_type(4)));
typedef bf16   bf16x8 __attribute__((ext_vector_type(8)));

#define MTOT   25600   // 256*100 rows
#define CDIM   512
#define NTOK   100
#define RPAD   128     // padded K for R (cols 100..127 zeroed by memset)
#define BN_EPS 1e-5f
#define NW_T   (2048 * 512)          // trans_w elems
#define NW_L   (6 * 512 * 512)       // per weight-tensor elems (all layers)

// async 16B/lane global->LDS. LDS dest must be wave-uniform base + lane*16.
__device__ __forceinline__ void gload16(const bf16* gsrc, bf16* lds_dst)
{
    __builtin_amdgcn_global_load_lds(
        (const __attribute__((address_space(1))) void*)gsrc,
        (__attribute__((address_space(3))) void*)lds_dst,
        16, 0, 0);
}

// ---------------- fp32 -> bf16 elementwise convert (n % 4 == 0) ------------
__global__ __launch_bounds__(256) void k_cvt(const float* __restrict__ s,
                                             bf16* __restrict__ d, int n)
{
    const int i = (blockIdx.x * 256 + threadIdx.x) * 4;
    if (i < n) {
        const f32x4 v = *(const f32x4*)(s + i);
        bf16x4 o;
#pragma unroll
        for (int e = 0; e < 4; ++e) o[e] = (bf16)v[e];
        *(bf16x4*)(d + i) = o;
    }
}

// all five weight tensors in one dispatch (z selects)
__global__ __launch_bounds__(256) void k_cvtw(const float* tw, const float* gw,
                                              const float* t2, const float* pw,
                                              const float* wwp,
                                              bf16* twd, bf16* gwd, bf16* t2d,
                                              bf16* pwd, bf16* wwd)
{
    const float* s; bf16* d; int n;
    switch (blockIdx.z) {
        case 0: s = tw;  d = twd; n = NW_T; break;
        case 1: s = gw;  d = gwd; n = NW_L; break;
        case 2: s = t2;  d = t2d; n = NW_L; break;
        case 3: s = pw;  d = pwd; n = NW_L; break;
        default: s = wwp; d = wwd; n = NW_L; break;
    }
    const int i = (blockIdx.x * 256 + threadIdx.x) * 4;
    if (i < n) {
        const f32x4 v = *(const f32x4*)(s + i);
        bf16x4 o;
#pragma unroll
        for (int e = 0; e < 4; ++e) o[e] = (bf16)v[e];
        *(bf16x4*)(d + i) = o;
    }
}

// ---------------------------------------------------------------------------
// 128x128-tile GEMM mainloop: C += A[m0:,:] * W[n0:,:]^T, BK=32, K%32==0.
// A: MxK row-major (bf16 if ABF else fp32, converted in staging regs);
// W: 512xK row-major bf16. 4 waves (2x2 of 64x64), 4x4 16x16x32 MFMAs.
// bf16 operands staged via global_load_lds; slot s=tid(+256): LDS = base+16*s,
// wave-uniform base + lane*16 as required.
// ---------------------------------------------------------------------------
template<bool ABF>
__device__ __forceinline__ void gemm_tile(const void* __restrict__ Av,
                                          const bf16* __restrict__ W,
                                          int K, int m0, int n0,
                                          bf16* As, bf16* Bs, f32x4 acc[4][4])
{
    const int tid  = threadIdx.x;
    const int lane = tid & 63, wave = tid >> 6;
    const int lrow = lane & 15, quad = lane >> 4;
    const int wm = (wave & 1) * 64, wn = (wave >> 1) * 64;
    const int r0 = tid >> 2;             // staging row 0..63 (+64 for u=1)
    const int kp = (tid & 3) * 8;        // staging k-offset (elements)

    const bf16* Wb0 = W + (size_t)(n0 + r0) * K + kp;
    const bf16* Wb1 = Wb0 + (size_t)64 * K;
    bf16* As0 = As + tid * 8;            // 16B per slot
    bf16* Bs0 = Bs + tid * 8;

    const bf16*  Ab0 = ABF ? (const bf16*)Av + (size_t)(m0 + r0) * K + kp : (const bf16*)nullptr;
    const bf16*  Ab1 = ABF ? Ab0 + (size_t)64 * K : (const bf16*)nullptr;
    const float* Af0 = ABF ? (const float*)nullptr : (const float*)Av + (size_t)(m0 + r0) * K + kp;
    const float* Af1 = ABF ? (const float*)nullptr : Af0 + (size_t)64 * K;

    for (int kt = 0; kt < K; kt += 32) {
        bf16x8 av0, av1;
        if (!ABF) {   // fp32 A: load+convert in regs (overlaps prev MFMAs)
            const f32x4 a0 = *(const f32x4*)(Af0 + kt);
            const f32x4 a1 = *(const f32x4*)(Af0 + kt + 4);
            const f32x4 a2 = *(const f32x4*)(Af1 + kt);
            const f32x4 a3 = *(const f32x4*)(Af1 + kt + 4);
#pragma unroll
            for (int e = 0; e < 4; ++e) {
                av0[e] = (bf16)a0[e]; av0[e + 4] = (bf16)a1[e];
                av1[e] = (bf16)a2[e]; av1[e + 4] = (bf16)a3[e];
            }
        }
        __syncthreads();                 // all waves done reading LDS
        if (ABF) {
            gload16(Ab0 + kt, As0);
            gload16(Ab1 + kt, As0 + 2048);
        } else {
            *(bf16x8*)As0          = av0;
            *(bf16x8*)(As0 + 2048) = av1;
        }
        gload16(Wb0 + kt, Bs0);
        gload16(Wb1 + kt, Bs0 + 2048);
        __syncthreads();                 // staging complete (vmcnt/lgkm drain)

        bf16x8 af[4], bv[4];
#pragma unroll
        for (int i = 0; i < 4; ++i)
            af[i] = *(const bf16x8*)(As + (wm + i * 16 + lrow) * 32 + quad * 8);
#pragma unroll
        for (int j = 0; j < 4; ++j)
            bv[j] = *(const bf16x8*)(Bs + (wn + j * 16 + lrow) * 32 + quad * 8);
#pragma unroll
        for (int i = 0; i < 4; ++i)
#pragma unroll
            for (int j = 0; j < 4; ++j)
                acc[i][j] = __builtin_amdgcn_mfma_f32_16x16x32_bf16(
                    af[i], bv[j], acc[i][j], 0, 0, 0);
    }
}

// ---------------- Encoder: xf = img @ trans_w^T + b; optional xb shadow ----
template<bool ABF>
__global__ __launch_bounds__(256) void k_enc(const void* __restrict__ img,
                                             const bf16* __restrict__ Wt,
                                             const float* __restrict__ bias,
                                             float* __restrict__ xf,
                                             bf16* __restrict__ xb)
{
    __shared__ __align__(16) bf16 As[128 * 32];
    __shared__ __align__(16) bf16 Bs[128 * 32];
    const int m0 = blockIdx.y * 128, n0 = blockIdx.x * 128;
    f32x4 acc[4][4] = {};
    gemm_tile<ABF>(img, Wt, 2048, m0, n0, As, Bs, acc);

    const int tid = threadIdx.x, wave = tid >> 6, lane = tid & 63;
    const int lrow = lane & 15, quad = lane >> 4;
    const int wm = (wave & 1) * 64, wn = (wave >> 1) * 64;
#pragma unroll
    for (int j = 0; j < 4; ++j) {
        const int col = n0 + wn + j * 16 + lrow;
        const float b = bias[col];
#pragma unroll
        for (int i = 0; i < 4; ++i) {
            const int row0 = m0 + wm + i * 16 + quad * 4;
#pragma unroll
            for (int r = 0; r < 4; ++r) {
                const size_t idx = (size_t)(row0 + r) * CDIM + col;
                const float v = acc[i][j][r] + b;
                xf[idx] = v;
                if (xb) xb[idx] = (bf16)v;
            }
        }
    }
}

// ---------------- Projection(s): out = bf16(x @ W^T + b) -------------------
// grid.z in {1,2}: z==0 -> (W0,b0,o0), z==1 -> (W1,b1,o1). A = xb or xf.
template<bool ABF>
__global__ __launch_bounds__(256) void k_proj2(const void* __restrict__ x,
                                               const bf16* __restrict__ W0, const float* __restrict__ b0,
                                               bf16* __restrict__ o0,
                                               const bf16* __restrict__ W1, const float* __restrict__ b1,
                                               bf16* __restrict__ o1)
{
    __shared__ __align__(16) bf16 As[128 * 32];
    __shared__ __align__(16) bf16 Bs[128 * 32];
    const bf16*  W    = blockIdx.z ? W1 : W0;
    const float* bias = blockIdx.z ? b1 : b0;
    bf16*        out  = blockIdx.z ? o1 : o0;

    const int m0 = blockIdx.y * 128, n0 = blockIdx.x * 128;
    f32x4 acc[4][4] = {};
    gemm_tile<ABF>(x, W, 512, m0, n0, As, Bs, acc);

    const int tid = threadIdx.x, wave = tid >> 6, lane = tid & 63;
    const int lrow = lane & 15, quad = lane >> 4;
    const int wm = (wave & 1) * 64, wn = (wave >> 1) * 64;
#pragma unroll
    for (int j = 0; j < 4; ++j) {
        const int col = n0 + wn + j * 16 + lrow;
        const float b = bias[col];
#pragma unroll
        for (int i = 0; i < 4; ++i) {
            const int row0 = m0 + wm + i * 16 + quad * 4;
#pragma unroll
            for (int r = 0; r < 4; ++r)
                out[(size_t)(row0 + r) * CDIM + col] = (bf16)(acc[i][j][r] + b);
        }
    }
}

// ---------------- W-proj + BN(eval) + residual; optional xb shadow ---------
__global__ __launch_bounds__(256) void k_wproj(const bf16* __restrict__ Y,
                                               const bf16* __restrict__ Wt,
                                               const float* __restrict__ bias,
                                               const float* __restrict__ bng, const float* __restrict__ bnb,
                                               const float* __restrict__ bnm, const float* __restrict__ bnv,
                                               float* __restrict__ xf,
                                               bf16* __restrict__ xb)
{
    __shared__ __align__(16) bf16 As[128 * 32];
    __shared__ __align__(16) bf16 Bs[128 * 32];
    const int m0 = blockIdx.y * 128, n0 = blockIdx.x * 128;
    f32x4 acc[4][4] = {};
    gemm_tile<true>(Y, Wt, 512, m0, n0, As, Bs, acc);

    const int tid = threadIdx.x, wave = tid >> 6, lane = tid & 63;
    const int lrow = lane & 15, quad = lane >> 4;
    const int wm = (wave & 1) * 64, wn = (wave >> 1) * 64;
#pragma unroll
    for (int j = 0; j < 4; ++j) {
        const int col = n0 + wn + j * 16 + lrow;
        const float sc = bng[col] * rsqrtf(bnv[col] + BN_EPS);
        const float sh = (bias[col] - bnm[col]) * sc + bnb[col];
#pragma unroll
        for (int i = 0; i < 4; ++i) {
            const int row0 = m0 + wm + i * 16 + quad * 4;
#pragma unroll
            for (int r = 0; r < 4; ++r) {
                const size_t idx = (size_t)(row0 + r) * CDIM + col;
                const float v = xf[idx] + acc[i][j][r] * sc + sh;
                xf[idx] = v;
                if (xb) xb[idx] = (bf16)v;
            }
        }
    }
}

// ---------------- R = th @ ph^T / 100, per batch ---------------------------
__global__ __launch_bounds__(256) void k_R(const bf16* __restrict__ TH,
                                           const bf16* __restrict__ PH,
                                           bf16* __restrict__ R)
{
    const int b = blockIdx.x;
    const bf16* th = TH + (size_t)b * NTOK * CDIM;
    const bf16* ph = PH + (size_t)b * NTOK * CDIM;
    bf16* Rb = R + (size_t)b * NTOK * RPAD;
    const int tid = threadIdx.x, wave = tid >> 6, lane = tid & 63;
    const int lrow = lane & 15, quad = lane >> 4;

    f32x4 acc[2][7] = {};
    for (int kt = 0; kt < CDIM; kt += 32) {
        bf16x8 af[2], bv[7];
#pragma unroll
        for (int i = 0; i < 2; ++i) {
            int row = (wave * 2 + i) * 16 + lrow; if (row > 99) row = 99;
            af[i] = *(const bf16x8*)(th + (size_t)row * CDIM + kt + quad * 8);
        }
#pragma unroll
        for (int j = 0; j < 7; ++j) {
            int row = j * 16 + lrow; if (row > 99) row = 99;
            bv[j] = *(const bf16x8*)(ph + (size_t)row * CDIM + kt + quad * 8);
        }
#pragma unroll
        for (int i = 0; i < 2; ++i)
#pragma unroll
            for (int j = 0; j < 7; ++j)
                acc[i][j] = __builtin_amdgcn_mfma_f32_16x16x32_bf16(
                    af[i], bv[j], acc[i][j], 0, 0, 0);
    }
#pragma unroll
    for (int i = 0; i < 2; ++i) {
        const int row0 = (wave * 2 + i) * 16 + quad * 4;
#pragma unroll
        for (int j = 0; j < 7; ++j) {
            const int col = j * 16 + lrow;
#pragma unroll
            for (int r = 0; r < 4; ++r) {
                const int row = row0 + r;
                if (row < NTOK && col < NTOK)
                    Rb[row * RPAD + col] = (bf16)(acc[i][j][r] * 0.01f);
            }
        }
    }
}

// ---------------- y = R @ g, per batch -------------------------------------
__global__ __launch_bounds__(256) void k_y(const bf16* __restrict__ R,
                                           const bf16* __restrict__ G,
                                           bf16* __restrict__ Y)
{
    const int b = blockIdx.y, cc0 = blockIdx.x * 128;
    const bf16* Rb = R + (size_t)b * NTOK * RPAD;
    const bf16* Gb = G + (size_t)b * NTOK * CDIM;
    bf16* Yb = Y + (size_t)b * NTOK * CDIM;
    __shared__ __align__(16) bf16 Bt[128 * 40];   // [col][k], stride 40
    const int tid = threadIdx.x, wave = tid >> 6, lane = tid & 63;
    const int lrow = lane & 15, quad = lane >> 4;

    f32x4 acc[7][2] = {};
    for (int kt = 0; kt < RPAD; kt += 32) {
        __syncthreads();
#pragma unroll
        for (int i = 0; i < 2; ++i) {
            const int chunk = tid * 2 + i;       // 0..511
            const int kk = chunk >> 4;           // 0..31
            const int c8 = (chunk & 15) * 8;     // col base 0..120
            uint4 v; v.x = v.y = v.z = v.w = 0u;
            if (kt + kk < NTOK)
                v = *(const uint4*)(Gb + (size_t)(kt + kk) * CDIM + cc0 + c8);
            const bf16* pv = (const bf16*)&v;
#pragma unroll
            for (int e = 0; e < 8; ++e) Bt[(c8 + e) * 40 + kk] = pv[e];
        }
        __syncthreads();
        bf16x8 af[7], bv[2];
#pragma unroll
        for (int mt = 0; mt < 7; ++mt) {
            int row = mt * 16 + lrow; if (row > 99) row = 99;
            af[mt] = *(const bf16x8*)(Rb + (size_t)row * RPAD + kt + quad * 8);
        }
#pragma unroll
        for (int jj = 0; jj < 2; ++jj)
            bv[jj] = *(const bf16x8*)(Bt + ((wave * 2 + jj) * 16 + lrow) * 40 + quad * 8);
#pragma unroll
        for (int mt = 0; mt < 7; ++mt)
#pragma unroll
            for (int jj = 0; jj < 2; ++jj)
                acc[mt][jj] = __builtin_amdgcn_mfma_f32_16x16x32_bf16(
                    af[mt], bv[jj], acc[mt][jj], 0, 0, 0);
    }
#pragma unroll
    for (int mt = 0; mt < 7; ++mt) {
        const int row0 = mt * 16 + quad * 4;
#pragma unroll
        for (int jj = 0; jj < 2; ++jj) {
            const int col = cc0 + (wave * 2 + jj) * 16 + lrow;
#pragma unroll
            for (int r = 0; r < 4; ++r) {
                const int row = row0 + r;
                if (row < NTOK) Yb[(size_t)row * CDIM + col] = (bf16)acc[mt][jj][r];
            }
        }
    }
}

// ---------------------------------------------------------------------------
extern "C" void kernel_launch(void* const* d_in, const int* in_sizes, int n_in,
                              void* d_out, int out_size, void* d_ws, size_t ws_size,
                              hipStream_t stream)
{
    const float* img     = (const float*)d_in[0];
    const float* trans_w = (const float*)d_in[1];
    const float* trans_b = (const float*)d_in[2];
    const float* gw = (const float*)d_in[3],  *gb = (const float*)d_in[4];
    const float* tw = (const float*)d_in[5],  *tb = (const float*)d_in[6];
    const float* pw = (const float*)d_in[7],  *pb = (const float*)d_in[8];
    const float* ww = (const float*)d_in[9],  *wb = (const float*)d_in[10];
    const float* bng = (const float*)d_in[11], *bnb = (const float*)d_in[12];
    const float* bnm = (const float*)d_in[13], *bnv = (const float*)d_in[14];

    float* xf = (float*)d_out;   // fp32 residual master == output

    // ws layout: weights | buf1 | buf2 | R | [xb] | [imgb]
    char* ws = (char*)d_ws;
    bf16* twbf = (bf16*)ws;                         // 2 MB
    bf16* gwbf = twbf + NW_T;
    bf16* t2bf = gwbf + NW_L;
    bf16* pwbf = t2bf + NW_L;
    bf16* wwbf = pwbf + NW_L;
    bf16* buf1 = wwbf + NW_L;                       // 26.2 MB
    bf16* buf2 = buf1 + (size_t)MTOT * CDIM;        // 26.2 MB
    bf16* R    = buf2 + (size_t)MTOT * CDIM;        // 6.55 MB
    bf16* xb   = R    + (size_t)256 * NTOK * RPAD;  // 26.2 MB
    bf16* imgb = xb   + (size_t)MTOT * CDIM;        // 104.9 MB

    const size_t MID_B  = (size_t)((char*)imgb - ws);                      //  99,876,864
    const size_t FULL_B = MID_B + (size_t)MTOT * 2048 * sizeof(bf16);      // 204,734,464
    const bool has_xb  = ws_size >= MID_B;
    const bool has_img = ws_size >= FULL_B;

    const size_t R_B = (size_t)256 * NTOK * RPAD * 2;
    hipMemsetAsync(R, 0, R_B, stream);              // zero K-pad cols of R

    const dim3 blk(256, 1, 1);
    k_cvtw<<<dim3(NW_L / 1024, 1, 5), blk, 0, stream>>>(trans_w, gw, tw, pw, ww,
                                                        twbf, gwbf, t2bf, pwbf, wwbf);
    if (has_img) {
        k_cvt<<<dim3(MTOT * 2048 / 1024), blk, 0, stream>>>(img, imgb, MTOT * 2048);
        k_enc<true><<<dim3(4, 200, 1), blk, 0, stream>>>(imgb, twbf, trans_b, xf,
                                                         has_xb ? xb : nullptr);
    } else {
        k_enc<false><<<dim3(4, 200, 1), blk, 0, stream>>>(img, twbf, trans_b, xf,
                                                          has_xb ? xb : nullptr);
    }

    for (int l = 0; l < 6; ++l) {
        const size_t wo = (size_t)l * CDIM * CDIM, bo = (size_t)l * CDIM;
        // th -> buf1, ph -> buf2
        if (has_xb)
            k_proj2<true><<<dim3(4, 200, 2), blk, 0, stream>>>(xb, t2bf + wo, tb + bo, buf1,
                                                               pwbf + wo, pb + bo, buf2);
        else
            k_proj2<false><<<dim3(4, 200, 2), blk, 0, stream>>>(xf, t2bf + wo, tb + bo, buf1,
                                                                pwbf + wo, pb + bo, buf2);
        k_R<<<dim3(256, 1, 1), blk, 0, stream>>>(buf1, buf2, R);
        // g -> buf1 (th dead)
        if (has_xb)
            k_proj2<true><<<dim3(4, 200, 1), blk, 0, stream>>>(xb, gwbf + wo, gb + bo, buf1,
                                                               gwbf + wo, gb + bo, buf1);
        else
            k_proj2<false><<<dim3(4, 200, 1), blk, 0, stream>>>(xf, gwbf + wo, gb + bo, buf1,
                                                                gwbf + wo, gb + bo, buf1);
        // y -> buf2 (ph dead)
        k_y<<<dim3(4, 256, 1), blk, 0, stream>>>(R, buf1, buf2);
        bf16* xbn = (has_xb && l < 5) ? xb : nullptr;
        k_wproj<<<dim3(4, 200, 1), blk, 0, stream>>>(buf2, wwbf + wo, wb + bo,
                                                     bng + bo, bnb + bo,
                                                     bnm + bo, bnv + bo, xf, xbn);
    }
}